// Round 2
// baseline (218.435 us; speedup 1.0000x reference)
//
#include <hip/hip_runtime.h>
#include <stdint.h>

// Problem constants
#define R_DIM 1024
#define B_DIM 16
#define D_DIM 256
#define S_DIM 20

// ---------------------------------------------------------------------------
// JAX threefry2x32: key = [0, 1234] (jax.random.key(1234)).
// Rotations {13,15,26,6} / {17,29,16,24}, ks2 = k0 ^ k1 ^ 0x1BD11BDA.
// Partitionable counter scheme (JAX >= 0.4.36 default): for flat index i,
// x0 = hi32(i) = 0 (size < 2^32), x1 = lo32(i) = i; bits = o0 ^ o1.
// ---------------------------------------------------------------------------
__device__ __forceinline__ void threefry2x32_1234(uint32_t x0, uint32_t x1,
                                                  uint32_t& o0, uint32_t& o1) {
  const uint32_t ks1 = 1234u;
  const uint32_t ks2 = 1234u ^ 0x1BD11BDAu;
  x1 += ks1;  // x0 += ks0 (=0)
#define TF_ROUND(r) { x0 += x1; x1 = (x1 << (r)) | (x1 >> (32 - (r))); x1 ^= x0; }
  TF_ROUND(13) TF_ROUND(15) TF_ROUND(26) TF_ROUND(6)
  x0 += ks1; x1 += ks2 + 1u;
  TF_ROUND(17) TF_ROUND(29) TF_ROUND(16) TF_ROUND(24)
  x0 += ks2; x1 += 2u;  // + ks0 (=0)
  TF_ROUND(13) TF_ROUND(15) TF_ROUND(26) TF_ROUND(6)
  x1 += ks1 + 3u;       // x0 += ks0 (=0)
  TF_ROUND(17) TF_ROUND(29) TF_ROUND(16) TF_ROUND(24)
  x0 += ks1; x1 += ks2 + 4u;
  TF_ROUND(13) TF_ROUND(15) TF_ROUND(26) TF_ROUND(6)
  x0 += ks2; x1 += 5u;  // + ks0 (=0)
#undef TF_ROUND
  o0 = x0; o1 = x1;
}

// 64-lane butterfly max of a uint64 key
__device__ __forceinline__ unsigned long long wave_max_u64(unsigned long long v) {
#pragma unroll
  for (int off = 1; off < 64; off <<= 1) {
    unsigned long long o = __shfl_xor(v, off, 64);
    v = (o > v) ? o : v;
  }
  return v;
}

// ---------------------------------------------------------------------------
// K1: out0[r][b][d] = vit_feature[b][d][r]   (tiled transpose, 32x32 per b)
// grid (R/32, D/32, B), block (32, 8)
// ---------------------------------------------------------------------------
__global__ __launch_bounds__(256) void k1_transpose(const float* __restrict__ vit,
                                                    float* __restrict__ out0) {
  __shared__ float tile[32][33];
  const int b = blockIdx.z;
  const int r0 = blockIdx.x * 32;
  const int d0 = blockIdx.y * 32;
  const int tx = threadIdx.x, ty = threadIdx.y;
  const float* src = vit + (size_t)b * D_DIM * R_DIM;
#pragma unroll
  for (int i = 0; i < 4; ++i) {
    int d = d0 + ty + i * 8;
    tile[ty + i * 8][tx] = src[(size_t)d * R_DIM + r0 + tx];
  }
  __syncthreads();
#pragma unroll
  for (int i = 0; i < 4; ++i) {
    int r = r0 + ty + i * 8;
    out0[((size_t)r * B_DIM + b) * D_DIM + d0 + tx] = tile[tx][ty + i * 8];
  }
}

// ---------------------------------------------------------------------------
// K2: per (b,r): cols = top4 over s<20 of lag_vit_map[b][s][r];
//     out1[(row*4+k)*256 + d] = lag_feature[b][cols[k]][d], row = r*16+b
// one wave per row; grid 4096 x 256
// ---------------------------------------------------------------------------
__global__ __launch_bounds__(256) void k2_lag(const float* __restrict__ lag_feature,
                                              const float* __restrict__ lag_vit_map,
                                              float* __restrict__ out1) {
  const int tid = blockIdx.x * blockDim.x + threadIdx.x;
  const int lane = threadIdx.x & 63;
  const int row = tid >> 6;          // 0..16383 = r*16 + b
  const int r = row >> 4;
  const int b = row & 15;

  unsigned long long key = 0ull;
  if (lane < S_DIM) {
    float f = lag_vit_map[((size_t)b * S_DIM + lane) * R_DIM + r];
    uint32_t u = __float_as_uint(f);
    uint32_t ok = u ^ (uint32_t)(((int32_t)u >> 31) | 0x80000000u);  // order-preserving
    key = ((unsigned long long)ok << 32) | (0xFFFFFFFFu - (uint32_t)lane);
  }

  uint32_t cols[4];
#pragma unroll
  for (int k = 0; k < 4; ++k) {
    unsigned long long m = wave_max_u64(key);
    cols[k] = 0xFFFFFFFFu - (uint32_t)m;
    if (key == m) key = 0ull;  // unique keys (index embedded)
  }

#pragma unroll
  for (int k = 0; k < 4; ++k) {
    const float4* src = (const float4*)(lag_feature + ((size_t)b * S_DIM + cols[k]) * D_DIM);
    float4* dst = (float4*)(out1 + ((size_t)row * 4 + k) * D_DIM);
    dst[lane] = src[lane];
  }
}

// ---------------------------------------------------------------------------
// K3: one wave per score-row (row = r*16+b, 16384 rows). Flat score index
//     i = row*1024 + s. Partitionable threefry: bits = o0^o1 of
//     threefry(key, 0, i). key = (bits>>9)<<32 | (~s); exclude s==r when b==15.
//     out2[(row*5+n)*256+d] = out0[(idx*16+15)*256+d]  (vit[15][d][idx])
// grid 4096 x 256
// ---------------------------------------------------------------------------
__device__ __forceinline__ void top5_mask(unsigned long long* keys, uint32_t* idx) {
#pragma unroll
  for (int n = 0; n < 5; ++n) {
    unsigned long long lm = keys[0];
#pragma unroll
    for (int t = 1; t < 16; ++t) lm = (keys[t] > lm) ? keys[t] : lm;
    unsigned long long g = wave_max_u64(lm);
    idx[n] = 0xFFFFFFFFu - (uint32_t)g;
#pragma unroll
    for (int t = 0; t < 16; ++t)
      if (keys[t] == g) keys[t] = 0ull;
  }
}

__global__ __launch_bounds__(256) void k3_neg(const float* __restrict__ out0,
                                              float* __restrict__ out2) {
  const int tid = blockIdx.x * blockDim.x + threadIdx.x;
  const int lane = threadIdx.x & 63;
  const int row = tid >> 6;          // 0..16383 = r*16 + b
  const int r = row >> 4, b = row & 15;

  unsigned long long keys[16];
  const uint32_t base = (uint32_t)row * 1024u;
#pragma unroll
  for (int t = 0; t < 16; ++t) {
    uint32_t s = (uint32_t)lane + ((uint32_t)t << 6);
    uint32_t o0, o1;
    threefry2x32_1234(0u, base + s, o0, o1);
    uint32_t bits = o0 ^ o1;
    unsigned long long k =
        ((unsigned long long)(bits >> 9) << 32) | (0xFFFFFFFFu - s);
    if (b == 15 && s == (uint32_t)r) k = 0ull;
    keys[t] = k;
  }

  uint32_t idx[5];
  top5_mask(keys, idx);

#pragma unroll
  for (int n = 0; n < 5; ++n) {
    const float4* src = (const float4*)(out0 + ((size_t)idx[n] * B_DIM + 15) * D_DIM);
    float4* dst = (float4*)(out2 + ((size_t)row * 5 + n) * D_DIM);
    dst[lane] = src[lane];
  }
}

// ---------------------------------------------------------------------------
extern "C" void kernel_launch(void* const* d_in, const int* in_sizes, int n_in,
                              void* d_out, int out_size, void* d_ws, size_t ws_size,
                              hipStream_t stream) {
  (void)in_sizes; (void)n_in; (void)d_ws; (void)ws_size; (void)out_size;
  const float* vit = (const float*)d_in[0];  // (16, 256, 1024)
  const float* lag = (const float*)d_in[1];  // (16, 20, 256)
  const float* map = (const float*)d_in[2];  // (16, 20, 1024)
  float* out = (float*)d_out;
  float* out0 = out;                                   // (1024,16,256)    = 4194304
  float* out1 = out + 4194304;                         // (1024,16,4,256)  = 16777216
  float* out2 = out + 4194304 + 16777216;              // (1024,16,5,256)  = 20971520

  dim3 g1(R_DIM / 32, D_DIM / 32, B_DIM), b1(32, 8);
  k1_transpose<<<g1, b1, 0, stream>>>(vit, out0);
  k2_lag<<<4096, 256, 0, stream>>>(lag, map, out1);
  k3_neg<<<4096, 256, 0, stream>>>(out0, out2);  // reads out0 (stream-ordered)
}

// Round 4
// 218.260 us; speedup vs baseline: 1.0008x; 1.0008x over previous
//
#include <hip/hip_runtime.h>
#include <stdint.h>

// Problem constants
#define R_DIM 1024
#define B_DIM 16
#define D_DIM 256
#define S_DIM 20

typedef float f32x4 __attribute__((ext_vector_type(4)));

// ---------------------------------------------------------------------------
// JAX threefry2x32, key = [0, 1234], partitionable counter scheme:
// for flat index i: x0 = 0, x1 = i; bits = o0 ^ o1.
// ---------------------------------------------------------------------------
__device__ __forceinline__ void threefry2x32_1234(uint32_t x0, uint32_t x1,
                                                  uint32_t& o0, uint32_t& o1) {
  const uint32_t ks1 = 1234u;
  const uint32_t ks2 = 1234u ^ 0x1BD11BDAu;
  x1 += ks1;  // x0 += ks0 (=0)
#define TF_ROUND(r) { x0 += x1; x1 = (x1 << (r)) | (x1 >> (32 - (r))); x1 ^= x0; }
  TF_ROUND(13) TF_ROUND(15) TF_ROUND(26) TF_ROUND(6)
  x0 += ks1; x1 += ks2 + 1u;
  TF_ROUND(17) TF_ROUND(29) TF_ROUND(16) TF_ROUND(24)
  x0 += ks2; x1 += 2u;  // + ks0 (=0)
  TF_ROUND(13) TF_ROUND(15) TF_ROUND(26) TF_ROUND(6)
  x1 += ks1 + 3u;       // x0 += ks0 (=0)
  TF_ROUND(17) TF_ROUND(29) TF_ROUND(16) TF_ROUND(24)
  x0 += ks1; x1 += ks2 + 4u;
  TF_ROUND(13) TF_ROUND(15) TF_ROUND(26) TF_ROUND(6)
  x0 += ks2; x1 += 5u;  // + ks0 (=0)
#undef TF_ROUND
  o0 = x0; o1 = x1;
}

// 64-lane butterfly max of a uint64 key
__device__ __forceinline__ unsigned long long wave_max_u64(unsigned long long v) {
#pragma unroll
  for (int off = 1; off < 64; off <<= 1) {
    unsigned long long o = __shfl_xor(v, off, 64);
    v = (o > v) ? o : v;
  }
  return v;
}

// ---------------------------------------------------------------------------
// Kernel A: blocks [0,4096)  -> transpose: out0[r][b][d] = vit[b][d][r]
//           blocks [4096,8192) -> top4-gather: out1 rows from lag_feature
// ---------------------------------------------------------------------------
__global__ __launch_bounds__(256) void kA(const float* __restrict__ vit,
                                          const float* __restrict__ lag_feature,
                                          const float* __restrict__ lag_vit_map,
                                          float* __restrict__ out0,
                                          float* __restrict__ out1) {
  if (blockIdx.x < 4096) {
    // ---- transpose part: 32x32 tile per block ----
    __shared__ float tile[32][33];
    const int id = blockIdx.x;
    const int bx = id & 31;          // r-tile
    const int by = (id >> 5) & 7;    // d-tile
    const int bz = id >> 8;          // b
    const int r0 = bx * 32, d0 = by * 32;
    const int tx = threadIdx.x & 31, ty = threadIdx.x >> 5;
    const float* src = vit + (size_t)bz * D_DIM * R_DIM;
#pragma unroll
    for (int i = 0; i < 4; ++i) {
      int d = d0 + ty + i * 8;
      tile[ty + i * 8][tx] = src[(size_t)d * R_DIM + r0 + tx];
    }
    __syncthreads();
    if (bz == 15) {
      // re-read by kernel B: keep cached
#pragma unroll
      for (int i = 0; i < 4; ++i) {
        int r = r0 + ty + i * 8;
        out0[((size_t)r * B_DIM + bz) * D_DIM + d0 + tx] = tile[tx][ty + i * 8];
      }
    } else {
      // never re-read: streaming store
#pragma unroll
      for (int i = 0; i < 4; ++i) {
        int r = r0 + ty + i * 8;
        __builtin_nontemporal_store(tile[tx][ty + i * 8],
                                    &out0[((size_t)r * B_DIM + bz) * D_DIM + d0 + tx]);
      }
    }
  } else {
    // ---- top4 gather part: one wave per (r,b) row ----
    const int tid = (blockIdx.x - 4096) * 256 + threadIdx.x;
    const int lane = threadIdx.x & 63;
    const int row = tid >> 6;        // r*16 + b
    const int r = row >> 4;
    const int b = row & 15;

    unsigned long long key = 0ull;
    if (lane < S_DIM) {
      float f = lag_vit_map[((size_t)b * S_DIM + lane) * R_DIM + r];
      uint32_t u = __float_as_uint(f);
      uint32_t ok = u ^ (uint32_t)(((int32_t)u >> 31) | 0x80000000u);
      key = ((unsigned long long)ok << 32) | (0xFFFFFFFFu - (uint32_t)lane);
    }

    uint32_t cols[4];
#pragma unroll
    for (int k = 0; k < 4; ++k) {
      unsigned long long m = wave_max_u64(key);
      cols[k] = 0xFFFFFFFFu - (uint32_t)m;
      if (key == m) key = 0ull;
    }

#pragma unroll
    for (int k = 0; k < 4; ++k) {
      const f32x4* src = (const f32x4*)(lag_feature + ((size_t)b * S_DIM + cols[k]) * D_DIM);
      f32x4* dst = (f32x4*)(out1 + ((size_t)row * 4 + k) * D_DIM);
      __builtin_nontemporal_store(src[lane], &dst[lane]);
    }
  }
}

// ---------------------------------------------------------------------------
// Kernel B: one wave per score-row (16384 rows). bits = o0^o1 of
// threefry(0, row*1024+s); key = (bits>>9)<<32 | ~s; exclude s==r when b==15.
// out2 row n = out0 row (idx*16+15)  (== vit[15][:, idx])
// ---------------------------------------------------------------------------
__device__ __forceinline__ void top5_mask(unsigned long long* keys, uint32_t* idx) {
#pragma unroll
  for (int n = 0; n < 5; ++n) {
    unsigned long long lm = keys[0];
#pragma unroll
    for (int t = 1; t < 16; ++t) lm = (keys[t] > lm) ? keys[t] : lm;
    unsigned long long g = wave_max_u64(lm);
    idx[n] = 0xFFFFFFFFu - (uint32_t)g;
#pragma unroll
    for (int t = 0; t < 16; ++t)
      if (keys[t] == g) keys[t] = 0ull;
  }
}

__global__ __launch_bounds__(256) void kB(const float* __restrict__ out0,
                                          float* __restrict__ out2) {
  const int tid = blockIdx.x * blockDim.x + threadIdx.x;
  const int lane = threadIdx.x & 63;
  const int row = tid >> 6;          // r*16 + b
  const int r = row >> 4, b = row & 15;

  unsigned long long keys[16];
  const uint32_t base = (uint32_t)row * 1024u;
#pragma unroll
  for (int t = 0; t < 16; ++t) {
    uint32_t s = (uint32_t)lane + ((uint32_t)t << 6);
    uint32_t o0, o1;
    threefry2x32_1234(0u, base + s, o0, o1);
    uint32_t bits = o0 ^ o1;
    unsigned long long k =
        ((unsigned long long)(bits >> 9) << 32) | (0xFFFFFFFFu - s);
    if (b == 15 && s == (uint32_t)r) k = 0ull;
    keys[t] = k;
  }

  uint32_t idx[5];
  top5_mask(keys, idx);

#pragma unroll
  for (int n = 0; n < 5; ++n) {
    const f32x4* src = (const f32x4*)(out0 + ((size_t)idx[n] * B_DIM + 15) * D_DIM);
    f32x4* dst = (f32x4*)(out2 + ((size_t)row * 5 + n) * D_DIM);
    __builtin_nontemporal_store(src[lane], &dst[lane]);
  }
}

// ---------------------------------------------------------------------------
extern "C" void kernel_launch(void* const* d_in, const int* in_sizes, int n_in,
                              void* d_out, int out_size, void* d_ws, size_t ws_size,
                              hipStream_t stream) {
  (void)in_sizes; (void)n_in; (void)d_ws; (void)ws_size; (void)out_size;
  const float* vit = (const float*)d_in[0];  // (16, 256, 1024)
  const float* lag = (const float*)d_in[1];  // (16, 20, 256)
  const float* map = (const float*)d_in[2];  // (16, 20, 1024)
  float* out = (float*)d_out;
  float* out0 = out;                                   // (1024,16,256)
  float* out1 = out + 4194304;                         // (1024,16,4,256)
  float* out2 = out + 4194304 + 16777216;              // (1024,16,5,256)

  kA<<<8192, 256, 0, stream>>>(vit, lag, map, out0, out1);
  kB<<<4096, 256, 0, stream>>>(out0, out2);  // reads out0 (stream-ordered)
}